// Round 14
// baseline (38.020 us; speedup 1.0000x reference)
//
#include <hip/hip_runtime.h>

constexpr int N_CTRL  = 25;
constexpr int IMG_H   = 256;
constexpr int IMG_W   = 192;
constexpr int BATCH   = 64;
constexpr int BCH     = 2;                   // batches per thread
constexpr int PLANE   = IMG_H * IMG_W;
constexpr int ROWPAIRS = IMG_H / 2;          // 128: thread owns rows 2r, 2r+1
constexpr int NWG = ROWPAIRS * (BATCH / BCH);// 4096, divisible by 8
constexpr float RBF_SCALE = 10.0f;
constexpr float OFF_SCALE = 0.3f;

typedef float vf2 __attribute__((ext_vector_type(2)));

__device__ __forceinline__ float bilin(float wx, float wy, vf2 r0, vf2 r1) {
    const float top = fmaf(wx, r0[1] - r0[0], r0[0]);
    const float bot = fmaf(wx, r1[1] - r1[0], r1[0]);
    return fmaf(wy, bot - top, top);
}

// 6 volatile gather loads for one (batch,row) unit; row-pair via offset:768.
#define LOAD6(PBASE, VA0, VA1, VB0, VB1, VC0, VC1) do {                        \
    const float* p0_ = (PBASE);                                                \
    const float* p1_ = p0_ + PLANE;                                            \
    const float* p2_ = p1_ + PLANE;                                            \
    asm volatile("global_load_dwordx2 %0, %1, off"            : "=v"(VA0) : "v"(p0_)); \
    asm volatile("global_load_dwordx2 %0, %1, off offset:768" : "=v"(VA1) : "v"(p0_)); \
    asm volatile("global_load_dwordx2 %0, %1, off"            : "=v"(VB0) : "v"(p1_)); \
    asm volatile("global_load_dwordx2 %0, %1, off offset:768" : "=v"(VB1) : "v"(p1_)); \
    asm volatile("global_load_dwordx2 %0, %1, off"            : "=v"(VC0) : "v"(p2_)); \
    asm volatile("global_load_dwordx2 %0, %1, off offset:768" : "=v"(VC1) : "v"(p2_)); \
} while (0)

// Counted wait pinning one unit's values (inputs AND outputs).
#define WAIT6(N, V0, V1, V2, V3, V4, V5)                                       \
    asm volatile("s_waitcnt vmcnt(" #N ")"                                     \
                 : "+v"(V0), "+v"(V1), "+v"(V2), "+v"(V3), "+v"(V4), "+v"(V5))

__global__ __launch_bounds__(192) void tps_warp_kernel(
    const float* __restrict__ cloth,   // (64,3,256,192)
    const float* __restrict__ theta,   // (64,50)
    float* __restrict__ out)           // (64,3,256,192)
{
    // XCD swizzle, 4 sequential phases per XCD (phase footprint 1.2 MB < L2).
    const int flat = blockIdx.x;
    const int xcd  = flat & 7;
    const int w    = flat >> 3;              // [0, 512)
    const int rp   = w & (ROWPAIRS - 1);     // row-pair index 0..127
    const int ph   = w >> 7;                 // phase 0..3
    const int b0   = (xcd * 4 + ph) * BCH;

    const int ww = threadIdx.x;              // 0..191 = full row width
    const int h0 = 2 * rp;
    const int h1 = h0 + 1;
    const float mx  = -1.0f + (2.0f / (IMG_W - 1)) * (float)ww;
    const float my0 = -1.0f + (2.0f / (IMG_H - 1)) * (float)h0;
    const float my1 = my0 + (2.0f / (IMG_H - 1));

    // Separable RBF: ex shared across the row pair -> 15 exps for 4 units.
#define RB(d) __expf(-(d) * (d) * RBF_SCALE)
    const float ex0 = RB(mx + 0.90f), ex1 = RB(mx + 0.45f), ex2 = RB(mx),
                ex3 = RB(mx - 0.45f), ex4 = RB(mx - 0.90f);
    const float ey00 = RB(my0 + 0.90f), ey01 = RB(my0 + 0.45f), ey02 = RB(my0),
                ey03 = RB(my0 - 0.45f), ey04 = RB(my0 - 0.90f);
    const float ey10 = RB(my1 + 0.90f), ey11 = RB(my1 + 0.45f), ey12 = RB(my1),
                ey13 = RB(my1 - 0.45f), ey14 = RB(my1 - 0.90f);
#undef RB

    // ---- phase A: 2 batches x 2 rows, named accumulators (no aggregates).
    const float* t0 = theta + (size_t)(b0 + 0) * (2 * N_CTRL);
    const float* t1 = theta + (size_t)(b0 + 1) * (2 * N_CTRL);
    float ox00 = 0, oy00 = 0, ox01 = 0, oy01 = 0;   // batch0: row0, row1
    float ox10 = 0, oy10 = 0, ox11 = 0, oy11 = 0;   // batch1: row0, row1
#define TERM(n, EX, EY0, EY1) {                                                \
    const float w0_ = OFF_SCALE * (EX) * (EY0);                                \
    const float w1_ = OFF_SCALE * (EX) * (EY1);                                \
    ox00 = fmaf(t0[2*(n)], w0_, ox00); oy00 = fmaf(t0[2*(n)+1], w0_, oy00);    \
    ox01 = fmaf(t0[2*(n)], w1_, ox01); oy01 = fmaf(t0[2*(n)+1], w1_, oy01);    \
    ox10 = fmaf(t1[2*(n)], w0_, ox10); oy10 = fmaf(t1[2*(n)+1], w0_, oy10);    \
    ox11 = fmaf(t1[2*(n)], w1_, ox11); oy11 = fmaf(t1[2*(n)+1], w1_, oy11); }
    TERM( 0, ex0, ey00, ey10) TERM( 1, ex1, ey00, ey10) TERM( 2, ex2, ey00, ey10) TERM( 3, ex3, ey00, ey10) TERM( 4, ex4, ey00, ey10)
    TERM( 5, ex0, ey01, ey11) TERM( 6, ex1, ey01, ey11) TERM( 7, ex2, ey01, ey11) TERM( 8, ex3, ey01, ey11) TERM( 9, ex4, ey01, ey11)
    TERM(10, ex0, ey02, ey12) TERM(11, ex1, ey02, ey12) TERM(12, ex2, ey02, ey12) TERM(13, ex3, ey02, ey12) TERM(14, ex4, ey02, ey12)
    TERM(15, ex0, ey03, ey13) TERM(16, ex1, ey03, ey13) TERM(17, ex2, ey03, ey13) TERM(18, ex3, ey03, ey13) TERM(19, ex4, ey03, ey13)
    TERM(20, ex0, ey04, ey14) TERM(21, ex1, ey04, ey14) TERM(22, ex2, ey04, ey14) TERM(23, ex3, ey04, ey14) TERM(24, ex4, ey04, ey14)
#undef TERM

#define COORD(OX, OY, MY, SX, SY)                                              \
    const float SX = (fminf(fmaxf(mx + (OX), -1.0f), 1.0f) + 1.0f) * (0.5f * (float)(IMG_W - 1)); \
    const float SY = (fminf(fmaxf((MY) + (OY), -1.0f), 1.0f) + 1.0f) * (0.5f * (float)(IMG_H - 1));
    COORD(ox00, oy00, my0, sx00, sy00)
    COORD(ox01, oy01, my1, sx01, sy01)
    COORD(ox10, oy10, my0, sx10, sy10)
    COORD(ox11, oy11, my1, sx11, sy11)
#undef COORD

    const size_t img_stride = (size_t)3 * PLANE;
    const float* imgb = cloth + (size_t)b0 * img_stride;

#define PBASE(B, SX, SY) (imgb + (size_t)(B) * img_stride +                    \
    (size_t)(min((int)(SY), IMG_H - 2) * IMG_W + min((int)(SX), IMG_W - 2)))

    // ---- phase B: 4 units, 2-deep counted-vmcnt pipeline. Unit order
    // (b0,r0),(b0,r1),(b1,r0),(b1,r1): consecutive units share the middle
    // input row (unit k's y0+1 == unit k+1's y0 when offsets are smooth) ->
    // the second touch is an L1 hit instead of a fresh line-miss. This is
    // the line-miss-reduction experiment (R13 refuted latency-starvation).
    vf2 a0, a1, a2, a3, a4, a5;        // (b0, r0)
    vf2 b0v, b1v, b2v, b3v, b4v, b5v;  // (b0, r1)
    vf2 c0, c1, c2, c3, c4, c5;        // (b1, r0)
    vf2 d0, d1, d2, d3, d4, d5;        // (b1, r1)
    float r000, r001, r002, r010, r011, r012;
    float r100, r101, r102, r110, r111, r112;

#define BLEND(SX, SY, V0, V1, V2, V3, V4, V5, R0, R1, R2) {                    \
    const float wx_ = (SX) - (float)min((int)(SX), IMG_W - 2);                 \
    const float wy_ = (SY) - (float)min((int)(SY), IMG_H - 2);                 \
    R0 = bilin(wx_, wy_, V0, V1);                                              \
    R1 = bilin(wx_, wy_, V2, V3);                                              \
    R2 = bilin(wx_, wy_, V4, V5); }

    LOAD6(PBASE(0, sx00, sy00), a0, a1, a2, a3, a4, a5);
    LOAD6(PBASE(0, sx01, sy01), b0v, b1v, b2v, b3v, b4v, b5v);
    WAIT6(6, a0, a1, a2, a3, a4, a5);
    BLEND(sx00, sy00, a0, a1, a2, a3, a4, a5, r000, r001, r002);
    LOAD6(PBASE(1, sx10, sy10), c0, c1, c2, c3, c4, c5);
    WAIT6(6, b0v, b1v, b2v, b3v, b4v, b5v);
    BLEND(sx01, sy01, b0v, b1v, b2v, b3v, b4v, b5v, r010, r011, r012);
    LOAD6(PBASE(1, sx11, sy11), d0, d1, d2, d3, d4, d5);
    WAIT6(6, c0, c1, c2, c3, c4, c5);
    BLEND(sx10, sy10, c0, c1, c2, c3, c4, c5, r100, r101, r102);
    WAIT6(0, d0, d1, d2, d3, d4, d5);
    BLEND(sx11, sy11, d0, d1, d2, d3, d4, d5, r110, r111, r112);
#undef BLEND
#undef PBASE

    // ---- phase C: 12 NT stores at the end.
    float* o00 = out + (size_t)(b0 + 0) * img_stride + h0 * IMG_W + ww;
    float* o01 = o00 + IMG_W;
    float* o10 = out + (size_t)(b0 + 1) * img_stride + h0 * IMG_W + ww;
    float* o11 = o10 + IMG_W;
    __builtin_nontemporal_store(r000, o00);
    __builtin_nontemporal_store(r001, o00 + PLANE);
    __builtin_nontemporal_store(r002, o00 + 2 * PLANE);
    __builtin_nontemporal_store(r010, o01);
    __builtin_nontemporal_store(r011, o01 + PLANE);
    __builtin_nontemporal_store(r012, o01 + 2 * PLANE);
    __builtin_nontemporal_store(r100, o10);
    __builtin_nontemporal_store(r101, o10 + PLANE);
    __builtin_nontemporal_store(r102, o10 + 2 * PLANE);
    __builtin_nontemporal_store(r110, o11);
    __builtin_nontemporal_store(r111, o11 + PLANE);
    __builtin_nontemporal_store(r112, o11 + 2 * PLANE);
}

extern "C" void kernel_launch(void* const* d_in, const int* in_sizes, int n_in,
                              void* d_out, int out_size, void* d_ws, size_t ws_size,
                              hipStream_t stream) {
    const float* cloth = (const float*)d_in[0];
    const float* theta = (const float*)d_in[1];
    float* out = (float*)d_out;

    tps_warp_kernel<<<dim3(NWG), dim3(192), 0, stream>>>(cloth, theta, out);
}

// Round 15
// 36.594 us; speedup vs baseline: 1.0390x; 1.0390x over previous
//
#include <hip/hip_runtime.h>

constexpr int GRID_SZ = 5;
constexpr int N_CTRL  = 25;
constexpr int IMG_H   = 256;
constexpr int IMG_W   = 192;
constexpr int BATCH   = 64;
constexpr int BCHUNK  = 2;    // batches per thread; 4 sequential phases per XCD
constexpr int PLANE   = IMG_H * IMG_W;
constexpr int PIX_BLOCKS = PLANE / 256;             // 192
constexpr int NWG = PIX_BLOCKS * (BATCH / BCHUNK);  // 6144
constexpr float RBF_SCALE = 10.0f;
constexpr float OFF_SCALE = 0.3f;

typedef float vf2 __attribute__((ext_vector_type(2)));

__device__ __forceinline__ float bilin(float wx, float wy, vf2 r0, vf2 r1) {
    const float top = fmaf(wx, r0[1] - r0[0], r0[0]);
    const float bot = fmaf(wx, r1[1] - r1[0], r1[0]);
    return fmaf(wy, bot - top, top);
}

// 6 volatile gather loads for one batch: 3 channel-pointers, row-pair via
// offset:768 (= IMG_W floats). Volatile asm: cannot be deleted/reordered/sunk.
#define LOAD6(PBASE, VA0, VA1, VB0, VB1, VC0, VC1) do {                        \
    const float* p0_ = (PBASE);                                                \
    const float* p1_ = p0_ + PLANE;                                            \
    const float* p2_ = p1_ + PLANE;                                            \
    asm volatile("global_load_dwordx2 %0, %1, off"            : "=v"(VA0) : "v"(p0_)); \
    asm volatile("global_load_dwordx2 %0, %1, off offset:768" : "=v"(VA1) : "v"(p0_)); \
    asm volatile("global_load_dwordx2 %0, %1, off"            : "=v"(VB0) : "v"(p1_)); \
    asm volatile("global_load_dwordx2 %0, %1, off offset:768" : "=v"(VB1) : "v"(p1_)); \
    asm volatile("global_load_dwordx2 %0, %1, off"            : "=v"(VC0) : "v"(p2_)); \
    asm volatile("global_load_dwordx2 %0, %1, off offset:768" : "=v"(VC1) : "v"(p2_)); \
} while (0)

// Counted wait that PINS one batch's values (inputs AND outputs): its loads
// must precede, its blends must follow. T4: never drain to 0 until the end.
#define WAIT6(N, V0, V1, V2, V3, V4, V5)                                       \
    asm volatile("s_waitcnt vmcnt(" #N ")"                                     \
                 : "+v"(V0), "+v"(V1), "+v"(V2), "+v"(V3), "+v"(V4), "+v"(V5))

__global__ __launch_bounds__(256, 4) void tps_warp_kernel(
    const float* __restrict__ cloth,   // (64,3,256,192)
    const float* __restrict__ theta,   // (64,50)
    float* __restrict__ out)           // (64,3,256,192)
{
    // XCD swizzle with 4 sequential phases per XCD (phase footprint ~1.2 MB
    // < 4 MiB private L2). Identical to R13.
    const int flat = blockIdx.x;
    const int xcd  = flat & 7;
    const int w    = flat >> 3;          // [0, 768) per XCD, dispatched in order
    const int pb   = w % PIX_BLOCKS;
    const int ph   = w / PIX_BLOCKS;     // phase 0..3, temporally sequential
    const int b0   = (xcd * 4 + ph) * BCHUNK;

    const int pix = pb * 256 + threadIdx.x;
    const int hh = pix / IMG_W;
    const int ww = pix - hh * IMG_W;
    const float mx = -1.0f + (2.0f / (IMG_W - 1)) * (float)ww;
    const float my = -1.0f + (2.0f / (IMG_H - 1)) * (float)hh;

    // Separable RBF basis — all named scalars (aggregates risk demotion).
#define RB(d) __expf(-(d) * (d) * RBF_SCALE)
    const float ex0 = RB(mx + 0.90f), ex1 = RB(mx + 0.45f), ex2 = RB(mx),
                ex3 = RB(mx - 0.45f), ex4 = RB(mx - 0.90f);
    const float ey0 = RB(my + 0.90f), ey1 = RB(my + 0.45f), ey2 = RB(my),
                ey3 = RB(my - 0.45f), ey4 = RB(my - 0.90f);
#undef RB

    // ---- phase A: 2 batches' offset accumulation, named accumulators.
    const float* t0 = theta + (size_t)(b0 + 0) * (2 * N_CTRL);
    const float* t1 = theta + (size_t)(b0 + 1) * (2 * N_CTRL);
    float ox0 = 0, oy0 = 0, ox1 = 0, oy1 = 0;
#define TERM(n, EX, EY) {                                                      \
    const float w_ = OFF_SCALE * (EX) * (EY);                                  \
    ox0 = fmaf(t0[2*(n)], w_, ox0); oy0 = fmaf(t0[2*(n)+1], w_, oy0);          \
    ox1 = fmaf(t1[2*(n)], w_, ox1); oy1 = fmaf(t1[2*(n)+1], w_, oy1); }
    TERM( 0, ex0, ey0) TERM( 1, ex1, ey0) TERM( 2, ex2, ey0) TERM( 3, ex3, ey0) TERM( 4, ex4, ey0)
    TERM( 5, ex0, ey1) TERM( 6, ex1, ey1) TERM( 7, ex2, ey1) TERM( 8, ex3, ey1) TERM( 9, ex4, ey1)
    TERM(10, ex0, ey2) TERM(11, ex1, ey2) TERM(12, ex2, ey2) TERM(13, ex3, ey2) TERM(14, ex4, ey2)
    TERM(15, ex0, ey3) TERM(16, ex1, ey3) TERM(17, ex2, ey3) TERM(18, ex3, ey3) TERM(19, ex4, ey3)
    TERM(20, ex0, ey4) TERM(21, ex1, ey4) TERM(22, ex2, ey4) TERM(23, ex3, ey4) TERM(24, ex4, ey4)
#undef TERM

#define COORD(OX, OY, SX, SY)                                                  \
    const float SX = (fminf(fmaxf(mx + (OX), -1.0f), 1.0f) + 1.0f) * (0.5f * (float)(IMG_W - 1)); \
    const float SY = (fminf(fmaxf(my + (OY), -1.0f), 1.0f) + 1.0f) * (0.5f * (float)(IMG_H - 1));
    COORD(ox0, oy0, sx0, sy0)
    COORD(ox1, oy1, sx1, sy1)
#undef COORD

    const size_t img_stride = (size_t)3 * PLANE;
    const float* imgb = cloth + (size_t)b0 * img_stride;
    float*       outb = out   + (size_t)b0 * img_stride + pix;

#define PBASE(B, SX, SY) (imgb + (size_t)(B) * img_stride +                    \
    (size_t)(min((int)(SY), IMG_H - 2) * IMG_W + min((int)(SX), IMG_W - 2)))

    // ---- phase B: depth-12 pipeline (both batches fully in flight),
    // counted waits pin each batch's consumes. Identical to R13.
    vf2 a0, a1, a2, a3, a4, a5;        // batch 0
    vf2 b0v, b1v, b2v, b3v, b4v, b5v;  // batch 1
    float r00, r01, r02, r10, r11, r12;

#define BLEND(SX, SY, V0, V1, V2, V3, V4, V5, R0, R1, R2) {                    \
    const float wx_ = (SX) - (float)min((int)(SX), IMG_W - 2);                 \
    const float wy_ = (SY) - (float)min((int)(SY), IMG_H - 2);                 \
    R0 = bilin(wx_, wy_, V0, V1);                                              \
    R1 = bilin(wx_, wy_, V2, V3);                                              \
    R2 = bilin(wx_, wy_, V4, V5); }

    LOAD6(PBASE(0, sx0, sy0), a0, a1, a2, a3, a4, a5);
    LOAD6(PBASE(1, sx1, sy1), b0v, b1v, b2v, b3v, b4v, b5v);
    WAIT6(6, a0, a1, a2, a3, a4, a5);
    BLEND(sx0, sy0, a0, a1, a2, a3, a4, a5, r00, r01, r02);
    WAIT6(0, b0v, b1v, b2v, b3v, b4v, b5v);
    BLEND(sx1, sy1, b0v, b1v, b2v, b3v, b4v, b5v, r10, r11, r12);
#undef BLEND
#undef PBASE

    // ---- phase C: REGULAR stores (the single change vs R13).
    // R15 experiment: NT stores bypass L2/L3 and couple kernel time to the
    // HBM write-drain rate (steady-state dispatches ran at exactly
    // WRITE_SIZE/dur = 0.74 TB/s). Regular stores land in L2 and spill to
    // the 256 MB L3, which can absorb all 37 MB dirty; HBM writeback
    // proceeds lazily, decoupled from kernel duration.
    float* o0 = outb;
    float* o1 = outb + img_stride;
    o0[0]         = r00;
    o0[PLANE]     = r01;
    o0[2 * PLANE] = r02;
    o1[0]         = r10;
    o1[PLANE]     = r11;
    o1[2 * PLANE] = r12;
}

extern "C" void kernel_launch(void* const* d_in, const int* in_sizes, int n_in,
                              void* d_out, int out_size, void* d_ws, size_t ws_size,
                              hipStream_t stream) {
    const float* cloth = (const float*)d_in[0];
    const float* theta = (const float*)d_in[1];
    float* out = (float*)d_out;

    tps_warp_kernel<<<dim3(NWG), dim3(256), 0, stream>>>(cloth, theta, out);
}